// Round 4
// baseline (176.698 us; speedup 1.0000x reference)
//
#include <hip/hip_runtime.h>

#define N_NODES 100000
#define N_EDGES 1600000
#define IN_F 128
#define OUT_F 64

#define BROWS 32               // rows per bucket (100000 = 32 * 3125)
#define NBUCKET 3125
#define CAP 1024               // max edges a gather block sorts (mean 512, std 22.6)
#define OVF 512                // overflow list (insurance; 22-44 sigma out)
#define BK_PAD 136             // padded k-stride (shorts) for b_lds: breaks 16-way bank repeat

#define NCHUNK 512             // edge chunks; 512-thr sort blocks -> 2 blocks/CU resident
#define EPC (N_EDGES / NCHUNK) // 3125 edges per chunk (exact)
#define NPOS (NBUCKET + 1)     // 3126: per-chunk prefix incl. sentinel

typedef __attribute__((ext_vector_type(8))) short bf16x8;
typedef __attribute__((ext_vector_type(4))) float f32x4;

__device__ __forceinline__ unsigned short f32_to_bf16(float f) {
    const unsigned int b = __float_as_uint(f);
    return (unsigned short)((b + 0x7FFFu + ((b >> 16) & 1u)) >> 16);   // RNE
}
__device__ __forceinline__ float bf16_to_f32(unsigned short u) {
    return __uint_as_float(((unsigned int)u) << 16);
}
// unpack low/high bf16 of a uint32 (1 VALU each)
__device__ __forceinline__ float bflo(unsigned int u) { return __uint_as_float(u << 16); }
__device__ __forceinline__ float bfhi(unsigned int u) { return __uint_as_float(u & 0xFFFF0000u); }

// ---------------- Kernel 1: support(bf16) = X @ W via MFMA 16x16x32 bf16 ----------------
// Block = 256 thr = 4 waves; wave handles 16 rows x 64 cols. W transposed in LDS
// as [n][k] bf16 (pad 136) so b-frags are ds_read_b128. A-frags read straight from
// global x (each element once, 32B/lane chunks). Frag layouts (m89/m91-verified):
// A: m=lane&15, k=quad*8+j.  B: n=lane&15, k=quad*8+j.  C/D: col=lane&15, row=quad*4+r.
__global__ __launch_bounds__(256) void gemm_kernel(
    const float* __restrict__ x, const float* __restrict__ w,
    unsigned short* __restrict__ support) {
    __shared__ unsigned short b_lds[OUT_F * BK_PAD];   // 17.4 KB

    const int t = threadIdx.x;
    #pragma unroll
    for (int i = 0; i < 8; ++i) {
        const int f = t + 256 * i;            // float4 index; k = f>>4, n4 = (f&15)*4
        const int k = f >> 4, n4 = (f & 15) * 4;
        const float4 wv = ((const float4*)w)[f];
        b_lds[(n4 + 0) * BK_PAD + k] = f32_to_bf16(wv.x);
        b_lds[(n4 + 1) * BK_PAD + k] = f32_to_bf16(wv.y);
        b_lds[(n4 + 2) * BK_PAD + k] = f32_to_bf16(wv.z);
        b_lds[(n4 + 3) * BK_PAD + k] = f32_to_bf16(wv.w);
    }
    __syncthreads();

    const int lane = t & 63, wid = t >> 6;
    const int m16 = lane & 15, quad = lane >> 4;
    const int row0 = blockIdx.x * 64 + wid * 16;
    const int arow = min(row0 + m16, N_NODES - 1);
    const float* xr = x + (size_t)arow * IN_F;

    f32x4 acc[4];
    #pragma unroll
    for (int nt = 0; nt < 4; ++nt) acc[nt] = (f32x4){0.f, 0.f, 0.f, 0.f};

    #pragma unroll
    for (int kt = 0; kt < 4; ++kt) {
        const int kb = kt * 32 + quad * 8;
        const float4 a0 = *(const float4*)(xr + kb);
        const float4 a1 = *(const float4*)(xr + kb + 4);
        bf16x8 af;
        af[0] = (short)f32_to_bf16(a0.x); af[1] = (short)f32_to_bf16(a0.y);
        af[2] = (short)f32_to_bf16(a0.z); af[3] = (short)f32_to_bf16(a0.w);
        af[4] = (short)f32_to_bf16(a1.x); af[5] = (short)f32_to_bf16(a1.y);
        af[6] = (short)f32_to_bf16(a1.z); af[7] = (short)f32_to_bf16(a1.w);
        #pragma unroll
        for (int nt = 0; nt < 4; ++nt) {
            const bf16x8 bf = *(const bf16x8*)&b_lds[(nt * 16 + m16) * BK_PAD + kb];
            acc[nt] = __builtin_amdgcn_mfma_f32_16x16x32_bf16(af, bf, acc[nt], 0, 0, 0);
        }
    }

    #pragma unroll
    for (int nt = 0; nt < 4; ++nt) {
        #pragma unroll
        for (int r = 0; r < 4; ++r) {
            const int row = row0 + quad * 4 + r;
            if (row < N_NODES)
                support[(size_t)row * OUT_F + nt * 16 + m16] = f32_to_bf16(acc[nt][r]);
        }
    }
}

// ---------------- Kernel 2: chunk-local bucket sort (fuses count+offs+base+reorder) ----------
// Block = chunk = 3125 edges, 512 threads, 37.5 KB LDS -> 4 blocks/CU fit, grid 512 =
// 2 resident blocks/CU (was 1 block/CU at 50% occupancy ceiling). LDS histogram ->
// block scan -> persist per-chunk prefix pos[c][*] (coalesced) -> LDS-rank scatter ->
// write sd chunk-contiguous (perfectly coalesced; no scattered global stores).
__global__ __launch_bounds__(512) void sort_kernel(
    const int* __restrict__ erow, const int* __restrict__ ecol,
    const float* __restrict__ evals, int* __restrict__ pos_g,
    uint2* __restrict__ sedge) {
    __shared__ uint2 sd[EPC];        // 25 KB bucket-sorted payloads
    __shared__ int pos[NPOS];        // 12.5 KB histogram -> prefix -> cursors
    __shared__ int wofs[8];

    const int t = threadIdx.x;
    const int c = blockIdx.x;
    const size_t e0 = (size_t)c * EPC;

    for (int i = t; i < NPOS; i += 512) pos[i] = 0;
    __syncthreads();

    // pass 1: histogram (erow re-read in pass 2 is L2-hot: 12.5 KB slice/block)
    #pragma unroll 1
    for (int j = t; j < EPC; j += 512)
        atomicAdd(&pos[erow[e0 + j] >> 5], 1);
    __syncthreads();

    // block-exclusive scan over 3125 buckets, 8 per thread (512*8 = 4096 >= 3126)
    int v[8]; int s = 0;
    #pragma unroll
    for (int j = 0; j < 8; ++j) {
        const int i = t * 8 + j;
        v[j] = (i < NBUCKET) ? pos[i] : 0;
        s += v[j];
    }
    const int lane = t & 63, wid = t >> 6;
    int incl = s;
    #pragma unroll
    for (int d = 1; d < 64; d <<= 1) { int tv = __shfl_up(incl, d); if (lane >= d) incl += tv; }
    if (lane == 63) wofs[wid] = incl;
    __syncthreads();
    int wbase = 0;
    #pragma unroll
    for (int wj = 0; wj < 8; ++wj) wbase += (wj < wid) ? wofs[wj] : 0;
    int ex = wbase + incl - s;
    #pragma unroll
    for (int j = 0; j < 8; ++j) {
        const int i = t * 8 + j;
        if (i < NBUCKET) { pos[i] = ex; ex += v[j]; }   // own indices only: no hazard
    }
    if (t == 0) pos[NBUCKET] = EPC;
    __syncthreads();

    // persist per-chunk prefix (coalesced)
    int* pg = pos_g + (size_t)c * NPOS;
    for (int i = t; i < NPOS; i += 512) pg[i] = pos[i];
    __syncthreads();   // persist reads must finish before cursors mutate

    // pass 2: rank + scatter to LDS
    #pragma unroll 1
    for (int j = t; j < EPC; j += 512) {
        const int row = erow[e0 + j];
        const int col = ecol[e0 + j];
        const float val = evals[e0 + j];
        const int r = atomicAdd(&pos[row >> 5], 1);
        uint2 ed;
        ed.x = (unsigned int)col | (((unsigned int)row & 31u) << 20);
        ed.y = __float_as_uint(val);
        sd[r] = ed;
    }
    __syncthreads();

    // write sorted chunk, fully coalesced
    uint2* sg = sedge + e0;
    for (int i = t; i < EPC; i += 512) sg[i] = sd[i];
}

// ---------------- Kernel 3: transpose pos[512][3126] -> posT[3126][512] ----------------
// Gather block k then reads rows k, k+1 of posT as two coalesced 2 KB loads.
__global__ __launch_bounds__(256) void transpose_kernel(
    const int* __restrict__ pos_g, int* __restrict__ posT) {
    __shared__ int tile[64][65];
    const int k0 = blockIdx.x * 64;
    const int c0 = blockIdx.y * 64;
    const int t = threadIdx.x;
    #pragma unroll
    for (int m = 0; m < 16; ++m) {
        const int idx = m * 256 + t;
        const int i = idx >> 6, j = idx & 63;     // i: local c, j: local k (contiguous read)
        const int cc = c0 + i, kk = k0 + j;
        if (cc < NCHUNK && kk < NPOS)
            tile[j][i] = pos_g[(size_t)cc * NPOS + kk];
    }
    __syncthreads();
    #pragma unroll
    for (int m = 0; m < 16; ++m) {
        const int idx = m * 256 + t;
        const int j = idx >> 6, i = idx & 63;     // i: local c (contiguous write)
        const int kk = k0 + j, cc = c0 + i;
        if (kk < NPOS && cc < NCHUNK)
            posT[(size_t)kk * NCHUNK + cc] = tile[j][i];
    }
}

// accumulate 8 edges (two quads) of one row into 4 col accumulators
#define QUAD8(A0, A1, A2, A3, J) do { \
    const uint2 q0 = sdata[(J) + eg], q1 = sdata[(J) + 4 + eg]; \
    const uint2 h0 = *(const uint2*)(support + (size_t)(q0.x & 0xFFFFFu) * OUT_F + c4 * 4); \
    const uint2 h1 = *(const uint2*)(support + (size_t)(q1.x & 0xFFFFFu) * OUT_F + c4 * 4); \
    const float w0 = __uint_as_float(q0.y), w1 = __uint_as_float(q1.y); \
    A0 += w0 * bflo(h0.x); A1 += w0 * bfhi(h0.x); A2 += w0 * bflo(h0.y); A3 += w0 * bfhi(h0.y); \
    A0 += w1 * bflo(h1.x); A1 += w1 * bfhi(h1.x); A2 += w1 * bflo(h1.y); A3 += w1 * bfhi(h1.y); \
} while (0)

// predicated quad tail (0..3 live edges of the 4-group)
#define QUADT(A0, A1, A2, A3, J, E) do { \
    const int jj = (J) + eg; const bool act = jj < (E); \
    const uint2 q = sdata[act ? jj : (J)]; \
    const float w = act ? __uint_as_float(q.y) : 0.f; \
    const uint2 h = *(const uint2*)(support + (size_t)(q.x & 0xFFFFFu) * OUT_F + c4 * 4); \
    A0 += w * bflo(h.x); A1 += w * bfhi(h.x); A2 += w * bflo(h.y); A3 += w * bfhi(h.y); \
} while (0)

// ---------------- Kernel 4: gather = two-pass run counting-sort + dual-row accumulation -----
// Thread t owns chunks t and t+256 (avg run = 1 edge). Pass 1 counts rows straight
// from the (L2/L3-hot) sedge runs; pass 2 places into sdata at LDS cursors. No tmp
// staging, no arrival scan (-8 KB LDS, -2 barriers vs r3). Accumulation: each wave
// processes ROW PAIRS concurrently -> 4 independent support gathers in flight
// (latency-bound chain, was 2). Bijective XCD swizzle for sedge/posT L2 locality.
__global__ __launch_bounds__(256) void gather_kernel(
    const unsigned short* __restrict__ support, const uint2* __restrict__ sedge,
    const int* __restrict__ posT, const float* __restrict__ bias,
    float* __restrict__ out) {
    __shared__ uint2 sdata[CAP];    // 8 KB row-sorted edges
    __shared__ uint2 ovf[OVF];      // 4 KB overflow list (statistically never used)
    __shared__ int bcnt[BROWS];
    __shared__ int bptr[BROWS + 1];
    __shared__ int boff[BROWS];
    __shared__ int ovn;

    const int t = threadIdx.x;
    // nwg = 3125 = 8*390 + 5: xcd<5 owns 391 buckets, else 390 (bijective, m204)
    const int orig = blockIdx.x;
    const int xcd = orig & 7, loc = orig >> 3;
    const int k = (xcd < 5 ? xcd * 391 : 5 * 391 + (xcd - 5) * 390) + loc;
    const int lane = t & 63, wid = t >> 6;

    // run descriptors for chunks t and t+256 (coalesced posT rows)
    int rs[2], re[2];
    #pragma unroll
    for (int cc = 0; cc < 2; ++cc) {
        const int c = t + cc * 256;
        rs[cc] = posT[(size_t)k * NCHUNK + c];
        re[cc] = posT[(size_t)(k + 1) * NCHUNK + c];
    }
    if (t < BROWS) bcnt[t] = 0;
    if (t == 0) ovn = 0;
    __syncthreads();

    // pass 1: count rows-in-bucket
    #pragma unroll
    for (int cc = 0; cc < 2; ++cc) {
        const size_t cbase = (size_t)(t + cc * 256) * EPC;
        for (int j = rs[cc]; j < re[cc]; ++j) {
            const unsigned rx = sedge[cbase + j].x;
            atomicAdd(&bcnt[(rx >> 20) & 31], 1);
        }
    }
    __syncthreads();

    if (t < 64) {
        const int v = (t < BROWS) ? bcnt[t] : 0;
        int incl = v;
        #pragma unroll
        for (int d = 1; d < 32; d <<= 1) { int tv = __shfl_up(incl, d); if (t >= d) incl += tv; }
        if (t < BROWS) { bptr[t] = incl - v; boff[t] = incl - v; }
        if (t == BROWS - 1) bptr[BROWS] = incl;
    }
    __syncthreads();
    const int nov_hint = bptr[BROWS] > CAP;   // uniform; practically always 0

    // pass 2: place into sdata (runs are L2-hot from pass 1)
    #pragma unroll
    for (int cc = 0; cc < 2; ++cc) {
        const size_t cbase = (size_t)(t + cc * 256) * EPC;
        for (int j = rs[cc]; j < re[cc]; ++j) {
            const uint2 ed = sedge[cbase + j];
            const int p = atomicAdd(&boff[(ed.x >> 20) & 31], 1);
            if (p < CAP) sdata[p] = ed;
            else { const int q = atomicAdd(&ovn, 1); if (q < OVF) ovf[q] = ed; }
        }
    }
    __syncthreads();

    const int eg = lane >> 4;          // edge-group 0..3
    const int c4 = lane & 15;          // col-quad: cols 4*c4 .. 4*c4+3
    const float4 bb = ((const float4*)bias)[c4];

    #pragma unroll 1
    for (int u = 0; u < 4; ++u) {
        const int rA = wid * 8 + u * 2, rB = rA + 1;
        int jA = min(bptr[rA], CAP);
        const int eA = min(bptr[rA + 1], CAP);
        int jB = eA;
        const int eB = min(bptr[rB + 1], CAP);
        float a0 = 0.f, a1 = 0.f, a2 = 0.f, a3 = 0.f;
        float b0 = 0.f, b1 = 0.f, b2 = 0.f, b3 = 0.f;
        // dual-row steady state: 4 support gathers in flight
        while (jA + 8 <= eA && jB + 8 <= eB) {
            QUAD8(a0, a1, a2, a3, jA);
            QUAD8(b0, b1, b2, b3, jB);
            jA += 8; jB += 8;
        }
        // drain A
        for (; jA + 8 <= eA; jA += 8) QUAD8(a0, a1, a2, a3, jA);
        for (; jA < eA; jA += 4) QUADT(a0, a1, a2, a3, jA, eA);
        // drain B
        for (; jB + 8 <= eB; jB += 8) QUAD8(b0, b1, b2, b3, jB);
        for (; jB < eB; jB += 4) QUADT(b0, b1, b2, b3, jB, eB);
        // cross-group reduce + store both rows
        a0 += __shfl_xor(a0, 16); a0 += __shfl_xor(a0, 32);
        a1 += __shfl_xor(a1, 16); a1 += __shfl_xor(a1, 32);
        a2 += __shfl_xor(a2, 16); a2 += __shfl_xor(a2, 32);
        a3 += __shfl_xor(a3, 16); a3 += __shfl_xor(a3, 32);
        b0 += __shfl_xor(b0, 16); b0 += __shfl_xor(b0, 32);
        b1 += __shfl_xor(b1, 16); b1 += __shfl_xor(b1, 32);
        b2 += __shfl_xor(b2, 16); b2 += __shfl_xor(b2, 32);
        b3 += __shfl_xor(b3, 16); b3 += __shfl_xor(b3, 32);
        if (eg == 0) {
            float4 oA, oB;
            oA.x = a0 + bb.x; oA.y = a1 + bb.y; oA.z = a2 + bb.z; oA.w = a3 + bb.w;
            oB.x = b0 + bb.x; oB.y = b1 + bb.y; oB.z = b2 + bb.z; oB.w = b3 + bb.w;
            *(float4*)(out + (size_t)(k * BROWS + rA) * OUT_F + c4 * 4) = oA;
            *(float4*)(out + (size_t)(k * BROWS + rB) * OUT_F + c4 * 4) = oB;
        }
    }

    if (nov_hint) {   // overflow insurance (CAP is 22 sigma above the mean bucket size)
        __syncthreads();                       // out overwrite-stores drained (vmcnt@barrier)
        const int nov = min(ovn, OVF);
        for (int i = wid; i < nov; i += 4) {   // wave per edge, lane = column
            const uint2 ed = ovf[i];
            const float g = bf16_to_f32(support[(size_t)(ed.x & 0xFFFFFu) * OUT_F + lane]);
            atomicAdd(&out[(size_t)(k * BROWS + ((ed.x >> 20) & 31)) * OUT_F + lane],
                      g * __uint_as_float(ed.y));
        }
    }
}

// ---------------- Fallback (ws too small): bias-init + atomic scatter ----------------
__global__ __launch_bounds__(256) void init_out_kernel(const float* __restrict__ bias,
                                                       float* __restrict__ out) {
    const size_t i = (size_t)blockIdx.x * 256 + threadIdx.x;
    if (i < (size_t)N_NODES * OUT_F) out[i] = bias[i & 63];
}
__global__ __launch_bounds__(256) void scatter_atomic_kernel(
    const unsigned short* __restrict__ support, const int* __restrict__ erow,
    const int* __restrict__ ecol, const float* __restrict__ evals,
    float* __restrict__ out) {
    const int wid = (blockIdx.x * 256 + threadIdx.x) >> 6;
    const int nw = gridDim.x * 4;
    const int lane = threadIdx.x & 63;
    const int n_iters = N_EDGES / 8;
    for (int it0 = wid; it0 < n_iters; it0 += nw) {
        const int e0 = __builtin_amdgcn_readfirstlane(it0) * 8;
        int src[8], dst[8]; float val[8];
        #pragma unroll
        for (int u = 0; u < 8; ++u) { src[u] = ecol[e0 + u]; dst[u] = erow[e0 + u]; val[u] = evals[e0 + u]; }
        float g[8];
        #pragma unroll
        for (int u = 0; u < 8; ++u) g[u] = bf16_to_f32(support[(size_t)src[u] * OUT_F + lane]);
        #pragma unroll
        for (int u = 0; u < 8; ++u) atomicAdd(&out[(size_t)dst[u] * OUT_F + lane], g[u] * val[u]);
    }
}

extern "C" void kernel_launch(void* const* d_in, const int* in_sizes, int n_in,
                              void* d_out, int out_size, void* d_ws, size_t ws_size,
                              hipStream_t stream) {
    const float* x     = (const float*)d_in[0];
    const float* w     = (const float*)d_in[1];
    const float* bias  = (const float*)d_in[2];
    const int* erow    = (const int*)d_in[3];
    const int* ecol    = (const int*)d_in[4];
    const float* evals = (const float*)d_in[5];
    float* out = (float*)d_out;

    char* p = (char*)d_ws;
    unsigned short* support = (unsigned short*)p;  size_t o = (size_t)N_NODES * OUT_F * 2;   // 12.8 MB
    int* pos_g = (int*)(p + o);                    o += (size_t)NCHUNK * NPOS * 4;            // 6.4 MB
    int* posT  = (int*)(p + o);                    o += (size_t)NPOS * NCHUNK * 4;            // 6.4 MB
    uint2* sedge = (uint2*)(p + o);                o += (size_t)N_EDGES * 8;                  // 12.8 MB

    gemm_kernel<<<(N_NODES + 63) / 64, 256, 0, stream>>>(x, w, support);

    if (ws_size >= o) {
        sort_kernel<<<NCHUNK, 512, 0, stream>>>(erow, ecol, evals, pos_g, sedge);
        transpose_kernel<<<dim3((NPOS + 63) / 64, NCHUNK / 64), 256, 0, stream>>>(pos_g, posT);
        gather_kernel<<<NBUCKET, 256, 0, stream>>>(support, sedge, posT, bias, out);
    } else {
        init_out_kernel<<<((N_NODES * OUT_F) + 255) / 256, 256, 0, stream>>>(bias, out);
        scatter_atomic_kernel<<<2048, 256, 0, stream>>>(support, erow, ecol, evals, out);
    }
}

// Round 5
// 167.032 us; speedup vs baseline: 1.0579x; 1.0579x over previous
//
#include <hip/hip_runtime.h>

#define N_NODES 100000
#define N_EDGES 1600000
#define IN_F 128
#define OUT_F 64

#define BROWS 32               // rows per bucket (100000 = 32 * 3125)
#define NBUCKET 3125
#define CAP 1024               // max edges a gather block sorts (mean 512, std 22.6)
#define BK_PAD 136             // padded k-stride (shorts) for b_lds: breaks 16-way bank repeat

#define NCHUNK 256             // edge chunks; == gather blockDim so thread==chunk
#define EPC (N_EDGES / NCHUNK) // 6250 edges per chunk (exact)
#define NPOS (NBUCKET + 1)     // 3126: per-chunk prefix incl. sentinel
#define GEMM_BLKS ((N_NODES + 127) / 128)   // 782: gemm sub-blocks (128 rows each)

typedef __attribute__((ext_vector_type(8))) short bf16x8;
typedef __attribute__((ext_vector_type(4))) float f32x4;

__device__ __forceinline__ unsigned short f32_to_bf16(float f) {
    const unsigned int b = __float_as_uint(f);
    return (unsigned short)((b + 0x7FFFu + ((b >> 16) & 1u)) >> 16);   // RNE
}
__device__ __forceinline__ float bf16_to_f32(unsigned short u) {
    return __uint_as_float(((unsigned int)u) << 16);
}
// unpack low/high bf16 of a uint32 (1 VALU each)
__device__ __forceinline__ float bflo(unsigned int u) { return __uint_as_float(u << 16); }
__device__ __forceinline__ float bfhi(unsigned int u) { return __uint_as_float(u & 0xFFFF0000u); }

// ---------------- Kernel 1: FUSED  gemm (blocks >= NCHUNK) + chunk-sort (blocks < NCHUNK) ----
// The two phases touch disjoint inputs (x,w vs edge arrays) and disjoint CUs, so they
// overlap instead of serializing across a launch boundary (~10us/launch + ~15us traffic).
//
// gemm: 512 thr = 8 waves; wave = 16 rows x 64 cols via MFMA 16x16x32 bf16. W transposed
// in LDS as [n][k] bf16 (pad 136) -> b-frags are ds_read_b128. A-frags straight from
// global x. Frag layouts (m89/m91-verified): A: m=lane&15,k=quad*8+j. B: n=lane&15,
// k=quad*8+j. C/D: col=lane&15, row=quad*4+r.
//
// sort: block = chunk = 6250 edges. LDS histogram -> block scan -> persist per-chunk
// prefix pos_g[c][*] (coalesced) -> LDS-rank scatter -> write sd chunk-contiguous
// (perfectly coalesced; no scattered global stores anywhere in the pipeline).
__global__ __launch_bounds__(512) void gemm_sort_kernel(
    const float* __restrict__ x, const float* __restrict__ w,
    unsigned short* __restrict__ support,
    const int* __restrict__ erow, const int* __restrict__ ecol,
    const float* __restrict__ evals, int* __restrict__ pos_g,
    uint2* __restrict__ sedge) {
    __shared__ union {
        struct { uint2 sd[EPC]; int pos[NPOS]; int wofs[8]; } s;   // 62.6 KB (sort)
        unsigned short b[OUT_F * BK_PAD];                          // 17.4 KB (gemm)
    } u;

    const int t = threadIdx.x;

    if (blockIdx.x < NCHUNK) {
        // ================= sort branch =================
        int* pos = u.s.pos;
        uint2* sd = u.s.sd;
        const int c = blockIdx.x;
        const size_t e0 = (size_t)c * EPC;

        for (int i = t; i < NPOS; i += 512) pos[i] = 0;
        __syncthreads();

        // pass 1: histogram (erow re-read in pass 2 is L2-hot: 25 KB slice/block)
        #pragma unroll 1
        for (int j = t; j < EPC; j += 512)
            atomicAdd(&pos[erow[e0 + j] >> 5], 1);
        __syncthreads();

        // block-exclusive scan over 3125 buckets, 7 per thread (512*7 = 3584 >= 3126)
        int v[7]; int s = 0;
        #pragma unroll
        for (int j = 0; j < 7; ++j) {
            const int i = t * 7 + j;
            v[j] = (i < NBUCKET) ? pos[i] : 0;
            s += v[j];
        }
        const int lane = t & 63, wid = t >> 6;
        int incl = s;
        #pragma unroll
        for (int d = 1; d < 64; d <<= 1) { int tv = __shfl_up(incl, d); if (lane >= d) incl += tv; }
        if (lane == 63) u.s.wofs[wid] = incl;
        __syncthreads();
        int wbase = 0;
        #pragma unroll
        for (int wj = 0; wj < 8; ++wj) wbase += (wj < wid) ? u.s.wofs[wj] : 0;
        int ex = wbase + incl - s;
        #pragma unroll
        for (int j = 0; j < 7; ++j) {
            const int i = t * 7 + j;
            if (i < NBUCKET) { pos[i] = ex; ex += v[j]; }   // own indices only: no hazard
        }
        if (t == 0) pos[NBUCKET] = EPC;
        __syncthreads();

        // persist per-chunk prefix (coalesced); gather reads it directly (L2-resident)
        int* pg = pos_g + (size_t)c * NPOS;
        for (int i = t; i < NPOS; i += 512) pg[i] = pos[i];
        __syncthreads();   // persist reads must finish before cursors mutate

        // pass 2: rank + scatter to LDS
        #pragma unroll 1
        for (int j = t; j < EPC; j += 512) {
            const int row = erow[e0 + j];
            const int col = ecol[e0 + j];
            const float val = evals[e0 + j];
            const int r = atomicAdd(&pos[row >> 5], 1);
            uint2 ed;
            ed.x = (unsigned int)col | (((unsigned int)row & 31u) << 20);
            ed.y = __float_as_uint(val);
            sd[r] = ed;
        }
        __syncthreads();

        // write sorted chunk, fully coalesced
        uint2* sg = sedge + e0;
        for (int i = t; i < EPC; i += 512) sg[i] = sd[i];
        return;
    }

    // ================= gemm branch =================
    const int bb = blockIdx.x - NCHUNK;
    // stage W transposed: w[k][n] (fp32, coalesced float4) -> b[n*BK_PAD + k] (bf16)
    #pragma unroll
    for (int i = 0; i < 4; ++i) {
        const int f = t + 512 * i;            // float4 index; k = f>>4, n4 = (f&15)*4
        const int k = f >> 4, n4 = (f & 15) * 4;
        const float4 wv = ((const float4*)w)[f];
        u.b[(n4 + 0) * BK_PAD + k] = f32_to_bf16(wv.x);
        u.b[(n4 + 1) * BK_PAD + k] = f32_to_bf16(wv.y);
        u.b[(n4 + 2) * BK_PAD + k] = f32_to_bf16(wv.z);
        u.b[(n4 + 3) * BK_PAD + k] = f32_to_bf16(wv.w);
    }
    __syncthreads();

    const int lane = t & 63, wid = t >> 6;
    const int m16 = lane & 15, quad = lane >> 4;
    const int row0 = bb * 128 + wid * 16;
    const int arow = min(row0 + m16, N_NODES - 1);
    const float* xr = x + (size_t)arow * IN_F;

    f32x4 acc[4];
    #pragma unroll
    for (int nt = 0; nt < 4; ++nt) acc[nt] = (f32x4){0.f, 0.f, 0.f, 0.f};

    #pragma unroll
    for (int kt = 0; kt < 4; ++kt) {
        const int kb = kt * 32 + quad * 8;
        const float4 a0 = *(const float4*)(xr + kb);
        const float4 a1 = *(const float4*)(xr + kb + 4);
        bf16x8 af;
        af[0] = (short)f32_to_bf16(a0.x); af[1] = (short)f32_to_bf16(a0.y);
        af[2] = (short)f32_to_bf16(a0.z); af[3] = (short)f32_to_bf16(a0.w);
        af[4] = (short)f32_to_bf16(a1.x); af[5] = (short)f32_to_bf16(a1.y);
        af[6] = (short)f32_to_bf16(a1.z); af[7] = (short)f32_to_bf16(a1.w);
        #pragma unroll
        for (int nt = 0; nt < 4; ++nt) {
            const bf16x8 bf = *(const bf16x8*)&u.b[(nt * 16 + m16) * BK_PAD + kb];
            acc[nt] = __builtin_amdgcn_mfma_f32_16x16x32_bf16(af, bf, acc[nt], 0, 0, 0);
        }
    }

    #pragma unroll
    for (int nt = 0; nt < 4; ++nt) {
        #pragma unroll
        for (int r = 0; r < 4; ++r) {
            const int row = row0 + quad * 4 + r;
            if (row < N_NODES)
                support[(size_t)row * OUT_F + nt * 16 + m16] = f32_to_bf16(acc[nt][r]);
        }
    }
}

// accumulate 8 edges (two quads) of one row into 4 col accumulators
#define QUAD8(A0, A1, A2, A3, J) do { \
    const uint2 q0 = sdata[(J) + eg], q1 = sdata[(J) + 4 + eg]; \
    const uint2 h0 = *(const uint2*)(support + (size_t)(q0.x & 0xFFFFFu) * OUT_F + c4 * 4); \
    const uint2 h1 = *(const uint2*)(support + (size_t)(q1.x & 0xFFFFFu) * OUT_F + c4 * 4); \
    const float w0 = __uint_as_float(q0.y), w1 = __uint_as_float(q1.y); \
    A0 += w0 * bflo(h0.x); A1 += w0 * bfhi(h0.x); A2 += w0 * bflo(h0.y); A3 += w0 * bfhi(h0.y); \
    A0 += w1 * bflo(h1.x); A1 += w1 * bfhi(h1.x); A2 += w1 * bflo(h1.y); A3 += w1 * bfhi(h1.y); \
} while (0)

// predicated quad tail (0..3 live edges of the 4-group)
#define QUADT(A0, A1, A2, A3, J, E) do { \
    const int jj = (J) + eg; const bool act = jj < (E); \
    const uint2 q = sdata[act ? jj : (J)]; \
    const float w = act ? __uint_as_float(q.y) : 0.f; \
    const uint2 h = *(const uint2*)(support + (size_t)(q.x & 0xFFFFFu) * OUT_F + c4 * 4); \
    A0 += w * bflo(h.x); A1 += w * bfhi(h.x); A2 += w * bflo(h.y); A3 += w * bfhi(h.y); \
} while (0)

// ---------------- Kernel 2: gather = run-fetch + counting-sort by row + accumulation ---------
// Thread t = chunk t; run bounds read DIRECTLY from pos_g[t][k..k+1] (one cache line;
// pos_g = 3.2 MB -> L2-resident per XCD; kills the transpose kernel + launch).
// Single pass over the (L2/L3-hot) sedge runs into tmp (arrival order, proven r3
// front-end @44.4us), then 32-way counting sort into sdata, then DUAL-ROW
// accumulation: each wave processes row pairs -> 4 independent support gathers in
// flight on the latency-bound chain. Bijective XCD swizzle for sedge/posT locality.
__global__ __launch_bounds__(256) void gather_kernel(
    const unsigned short* __restrict__ support, const uint2* __restrict__ sedge,
    const int* __restrict__ pos_g, const float* __restrict__ bias,
    float* __restrict__ out) {
    __shared__ uint2 tmp[CAP];      // 8 KB arrival-order edges
    __shared__ uint2 sdata[CAP];    // 8 KB row-sorted edges
    __shared__ int bcnt[BROWS];
    __shared__ int bptr[BROWS + 1];
    __shared__ int boff[BROWS];
    __shared__ int wsum[4];

    const int t = threadIdx.x;
    // nwg = 3125 = 8*390 + 5: xcd<5 owns 391 buckets, else 390 (bijective, m204)
    const int orig = blockIdx.x;
    const int xcd = orig & 7, loc = orig >> 3;
    const int k = (xcd < 5 ? xcd * 391 : 5 * 391 + (xcd - 5) * 390) + loc;
    const int lane = t & 63, wid = t >> 6;

    // run descriptor for chunk t: pos_g[t][k], pos_g[t][k+1] share one 64B line
    const int s = pos_g[(size_t)t * NPOS + k];
    const int e = pos_g[(size_t)t * NPOS + k + 1];
    const int L = e - s;

    // block scan of run lengths -> arrival offset
    int incl = L;
    #pragma unroll
    for (int d = 1; d < 64; d <<= 1) { int tv = __shfl_up(incl, d); if (lane >= d) incl += tv; }
    if (lane == 63) wsum[wid] = incl;
    if (t < BROWS) bcnt[t] = 0;
    __syncthreads();
    int wbase = 0;
    #pragma unroll
    for (int wj = 0; wj < 4; ++wj) wbase += (wj < wid) ? wsum[wj] : 0;
    const int ofs = wbase + incl - L;
    const int ntot = wsum[0] + wsum[1] + wsum[2] + wsum[3];
    const int n = min(ntot, CAP);

    // stash runs into tmp (arrival order); avg L = 2
    const uint2* myrun = sedge + (size_t)t * EPC + s;
    for (int j = 0; j < L; ++j) {
        const int p = ofs + j;
        if (p < CAP) tmp[p] = myrun[j];
    }
    __syncthreads();

    // counting sort by row-in-bucket
    uint2 my[4]; int mb[4];
    #pragma unroll
    for (int j = 0; j < 4; ++j) {
        const int i = t + j * 256;
        mb[j] = -1;
        if (i < n) {
            my[j] = tmp[i];
            mb[j] = (my[j].x >> 20) & 31;
            atomicAdd(&bcnt[mb[j]], 1);
        }
    }
    __syncthreads();

    if (t < 64) {
        const int v = (t < BROWS) ? bcnt[t] : 0;
        int incl2 = v;
        #pragma unroll
        for (int d = 1; d < 32; d <<= 1) { int tv = __shfl_up(incl2, d); if (t >= d) incl2 += tv; }
        if (t < BROWS) { bptr[t] = incl2 - v; boff[t] = incl2 - v; }
        if (t == BROWS - 1) bptr[BROWS] = incl2;
    }
    __syncthreads();

    #pragma unroll
    for (int j = 0; j < 4; ++j) {
        if (mb[j] >= 0) {
            const int p = atomicAdd(&boff[mb[j]], 1);
            sdata[p] = my[j];
        }
    }
    __syncthreads();

    const int eg = lane >> 4;          // edge-group 0..3
    const int c4 = lane & 15;          // col-quad: cols 4*c4 .. 4*c4+3
    const float4 bb = ((const float4*)bias)[c4];

    #pragma unroll 1
    for (int u = 0; u < 4; ++u) {
        const int rA = wid * 8 + u * 2, rB = rA + 1;
        int jA = min(bptr[rA], CAP);
        const int eA = min(bptr[rA + 1], CAP);
        int jB = eA;                          // bptr[rB] == bptr[rA+1]
        const int eB = min(bptr[rB + 1], CAP);
        float a0 = 0.f, a1 = 0.f, a2 = 0.f, a3 = 0.f;
        float b0 = 0.f, b1 = 0.f, b2 = 0.f, b3 = 0.f;
        // dual-row steady state: 4 support gathers in flight
        while (jA + 8 <= eA && jB + 8 <= eB) {
            QUAD8(a0, a1, a2, a3, jA);
            QUAD8(b0, b1, b2, b3, jB);
            jA += 8; jB += 8;
        }
        // drain A
        for (; jA + 8 <= eA; jA += 8) QUAD8(a0, a1, a2, a3, jA);
        for (; jA < eA; jA += 4) QUADT(a0, a1, a2, a3, jA, eA);
        // drain B
        for (; jB + 8 <= eB; jB += 8) QUAD8(b0, b1, b2, b3, jB);
        for (; jB < eB; jB += 4) QUADT(b0, b1, b2, b3, jB, eB);
        // cross-group reduce + store both rows
        a0 += __shfl_xor(a0, 16); a0 += __shfl_xor(a0, 32);
        a1 += __shfl_xor(a1, 16); a1 += __shfl_xor(a1, 32);
        a2 += __shfl_xor(a2, 16); a2 += __shfl_xor(a2, 32);
        a3 += __shfl_xor(a3, 16); a3 += __shfl_xor(a3, 32);
        b0 += __shfl_xor(b0, 16); b0 += __shfl_xor(b0, 32);
        b1 += __shfl_xor(b1, 16); b1 += __shfl_xor(b1, 32);
        b2 += __shfl_xor(b2, 16); b2 += __shfl_xor(b2, 32);
        b3 += __shfl_xor(b3, 16); b3 += __shfl_xor(b3, 32);
        if (eg == 0) {
            float4 oA, oB;
            oA.x = a0 + bb.x; oA.y = a1 + bb.y; oA.z = a2 + bb.z; oA.w = a3 + bb.w;
            oB.x = b0 + bb.x; oB.y = b1 + bb.y; oB.z = b2 + bb.z; oB.w = b3 + bb.w;
            *(float4*)(out + (size_t)(k * BROWS + rA) * OUT_F + c4 * 4) = oA;
            *(float4*)(out + (size_t)(k * BROWS + rB) * OUT_F + c4 * 4) = oB;
        }
    }

    if (ntot > CAP) {   // overflow insurance (CAP is 22 sigma above the mean bucket size)
        __syncthreads();                          // out stores done; tmp dead
        for (int j = 0; j < L; ++j) {
            const int p = ofs + j;
            if (p >= CAP && p - CAP < CAP) tmp[p - CAP] = myrun[j];
        }
        __syncthreads();
        const int nov = min(ntot - CAP, CAP);
        for (int i = wid; i < nov; i += 4) {      // wave per edge, lane = column
            const uint2 ed = tmp[i];
            const float g = bf16_to_f32(support[(size_t)(ed.x & 0xFFFFFu) * OUT_F + lane]);
            atomicAdd(&out[(size_t)(k * BROWS + ((ed.x >> 20) & 31)) * OUT_F + lane],
                      g * __uint_as_float(ed.y));
        }
    }
}

// ---------------- Fallback (ws too small): gemm-only + bias-init + atomic scatter ----------
__global__ __launch_bounds__(256) void gemm_kernel(
    const float* __restrict__ x, const float* __restrict__ w,
    unsigned short* __restrict__ support) {
    __shared__ unsigned short b_lds[OUT_F * BK_PAD];
    const int t = threadIdx.x;
    #pragma unroll
    for (int i = 0; i < 8; ++i) {
        const int f = t + 256 * i;
        const int k = f >> 4, n4 = (f & 15) * 4;
        const float4 wv = ((const float4*)w)[f];
        b_lds[(n4 + 0) * BK_PAD + k] = f32_to_bf16(wv.x);
        b_lds[(n4 + 1) * BK_PAD + k] = f32_to_bf16(wv.y);
        b_lds[(n4 + 2) * BK_PAD + k] = f32_to_bf16(wv.z);
        b_lds[(n4 + 3) * BK_PAD + k] = f32_to_bf16(wv.w);
    }
    __syncthreads();
    const int lane = t & 63, wid = t >> 6;
    const int m16 = lane & 15, quad = lane >> 4;
    const int row0 = blockIdx.x * 64 + wid * 16;
    const int arow = min(row0 + m16, N_NODES - 1);
    const float* xr = x + (size_t)arow * IN_F;
    f32x4 acc[4];
    #pragma unroll
    for (int nt = 0; nt < 4; ++nt) acc[nt] = (f32x4){0.f, 0.f, 0.f, 0.f};
    #pragma unroll
    for (int kt = 0; kt < 4; ++kt) {
        const int kb = kt * 32 + quad * 8;
        const float4 a0 = *(const float4*)(xr + kb);
        const float4 a1 = *(const float4*)(xr + kb + 4);
        bf16x8 af;
        af[0] = (short)f32_to_bf16(a0.x); af[1] = (short)f32_to_bf16(a0.y);
        af[2] = (short)f32_to_bf16(a0.z); af[3] = (short)f32_to_bf16(a0.w);
        af[4] = (short)f32_to_bf16(a1.x); af[5] = (short)f32_to_bf16(a1.y);
        af[6] = (short)f32_to_bf16(a1.z); af[7] = (short)f32_to_bf16(a1.w);
        #pragma unroll
        for (int nt = 0; nt < 4; ++nt) {
            const bf16x8 bf = *(const bf16x8*)&b_lds[(nt * 16 + m16) * BK_PAD + kb];
            acc[nt] = __builtin_amdgcn_mfma_f32_16x16x32_bf16(af, bf, acc[nt], 0, 0, 0);
        }
    }
    #pragma unroll
    for (int nt = 0; nt < 4; ++nt) {
        #pragma unroll
        for (int r = 0; r < 4; ++r) {
            const int row = row0 + quad * 4 + r;
            if (row < N_NODES)
                support[(size_t)row * OUT_F + nt * 16 + m16] = f32_to_bf16(acc[nt][r]);
        }
    }
}
__global__ __launch_bounds__(256) void init_out_kernel(const float* __restrict__ bias,
                                                       float* __restrict__ out) {
    const size_t i = (size_t)blockIdx.x * 256 + threadIdx.x;
    if (i < (size_t)N_NODES * OUT_F) out[i] = bias[i & 63];
}
__global__ __launch_bounds__(256) void scatter_atomic_kernel(
    const unsigned short* __restrict__ support, const int* __restrict__ erow,
    const int* __restrict__ ecol, const float* __restrict__ evals,
    float* __restrict__ out) {
    const int wid = (blockIdx.x * 256 + threadIdx.x) >> 6;
    const int nw = gridDim.x * 4;
    const int lane = threadIdx.x & 63;
    const int n_iters = N_EDGES / 8;
    for (int it0 = wid; it0 < n_iters; it0 += nw) {
        const int e0 = __builtin_amdgcn_readfirstlane(it0) * 8;
        int src[8], dst[8]; float val[8];
        #pragma unroll
        for (int u = 0; u < 8; ++u) { src[u] = ecol[e0 + u]; dst[u] = erow[e0 + u]; val[u] = evals[e0 + u]; }
        float g[8];
        #pragma unroll
        for (int u = 0; u < 8; ++u) g[u] = bf16_to_f32(support[(size_t)src[u] * OUT_F + lane]);
        #pragma unroll
        for (int u = 0; u < 8; ++u) atomicAdd(&out[(size_t)dst[u] * OUT_F + lane], g[u] * val[u]);
    }
}

extern "C" void kernel_launch(void* const* d_in, const int* in_sizes, int n_in,
                              void* d_out, int out_size, void* d_ws, size_t ws_size,
                              hipStream_t stream) {
    const float* x     = (const float*)d_in[0];
    const float* w     = (const float*)d_in[1];
    const float* bias  = (const float*)d_in[2];
    const int* erow    = (const int*)d_in[3];
    const int* ecol    = (const int*)d_in[4];
    const float* evals = (const float*)d_in[5];
    float* out = (float*)d_out;

    char* p = (char*)d_ws;
    unsigned short* support = (unsigned short*)p;  size_t o = (size_t)N_NODES * OUT_F * 2;   // 12.8 MB
    int* pos_g = (int*)(p + o);                    o += (size_t)NCHUNK * NPOS * 4;            // 3.2 MB
    uint2* sedge = (uint2*)(p + o);                o += (size_t)N_EDGES * 8;                  // 12.8 MB

    if (ws_size >= o) {
        gemm_sort_kernel<<<NCHUNK + GEMM_BLKS, 512, 0, stream>>>(
            x, w, support, erow, ecol, evals, pos_g, sedge);
        gather_kernel<<<NBUCKET, 256, 0, stream>>>(support, sedge, pos_g, bias, out);
    } else {
        gemm_kernel<<<(N_NODES + 63) / 64, 256, 0, stream>>>(x, w, support);
        init_out_kernel<<<((N_NODES * OUT_F) + 255) / 256, 256, 0, stream>>>(bias, out);
        scatter_atomic_kernel<<<2048, 256, 0, stream>>>(support, erow, ecol, evals, out);
    }
}